// Round 15
// baseline (120.538 us; speedup 1.0000x reference)
//
#include <hip/hip_runtime.h>
#include <hip/hip_bf16.h>

typedef __attribute__((ext_vector_type(4))) float f32x4;
typedef __attribute__((ext_vector_type(8))) int i32x8;
typedef __attribute__((ext_vector_type(2))) unsigned uintx2;
typedef const __attribute__((address_space(1))) void gvoid_t;
typedef __attribute__((address_space(3))) void lvoid_t;

#define ANGLE_COS 0.8775825618903728f  // cos(0.5)
#define ANGLE_SIN 0.4794255386042030f  // sin(0.5)
#define LOG2E 1.4426950408889634f
#define SCALE1 0x7F7F7F7Fu             // e8m0 exponent 127 = 2^0 in all bytes

static __device__ __forceinline__ float exp2_hw(float x) {
  return __builtin_amdgcn_exp2f(x);  // v_exp_f32: D = 2^S0
}

// pack 4 floats -> 4 OCP e4m3 bytes
static __device__ __forceinline__ unsigned pack4_fp8(float a, float b, float c, float d) {
  int v = __builtin_amdgcn_cvt_pk_fp8_f32(a, b, 0, false);   // bytes 0,1
  v = __builtin_amdgcn_cvt_pk_fp8_f32(c, d, v, true);        // bytes 2,3
  return (unsigned)v;
}

// ---- colprep: column inverse norms + fp8 w_norm*log2e in granule layout:
// granule (q,c) = 8B holding d = q*8..q*8+7 of column c, at wbn + (q*CT+c)*8.
__global__ __launch_bounds__(256) void colprep_kernel(
    const float* __restrict__ w, float* __restrict__ colinv,
    unsigned char* __restrict__ wbn, int C, int CT) {
  const int c = blockIdx.x * 256 + threadIdx.x;
  if (c >= CT) return;
  if (c >= C) {  // pad columns -> zeros (2^0=1, subtracted in reduce_loss)
    colinv[c] = 0.f;
    uintx2 z; z.x = 0; z.y = 0;
    #pragma unroll
    for (int q = 0; q < 16; ++q) *(uintx2*)(wbn + ((size_t)q * CT + c) * 8) = z;
    return;
  }
  float col[128];
  float s = 0.f;
  #pragma unroll
  for (int d = 0; d < 128; ++d) {
    col[d] = w[(size_t)d * C + c];
    s += col[d] * col[d];
  }
  const float inv = 1.0f / sqrtf(s);
  colinv[c] = inv;
  const float invl = inv * LOG2E;
  #pragma unroll
  for (int q = 0; q < 16; ++q) {
    uintx2 g;
    g.x = pack4_fp8(col[q*8+0]*invl, col[q*8+1]*invl, col[q*8+2]*invl, col[q*8+3]*invl);
    g.y = pack4_fp8(col[q*8+4]*invl, col[q*8+5]*invl, col[q*8+6]*invl, col[q*8+7]*invl);
    *(uintx2*)(wbn + ((size_t)q * CT + c) * 8) = g;
  }
}

// ---- colnorm only (fallback path when ws can't hold wbn) ----
__global__ void colnorm_kernel(const float* __restrict__ w, float* __restrict__ colinv, int C) {
  int c = blockIdx.x * 256 + threadIdx.x;
  if (c >= C) return;
  float s = 0.f;
  #pragma unroll 8
  for (int d = 0; d < 128; ++d) { float v = w[(size_t)d * C + c]; s += v * v; }
  colinv[c] = 1.0f / sqrtf(s);
}

// ---- fused: row-normalize -> fp8 Fn, plus fp32 target-column dot ->
// ct (cos theta) and cp (cos(theta+m)) per row. One shuffle pass for both.
__global__ void fnorm_tgtdot_kernel(const float* __restrict__ f, const float* __restrict__ w,
                                    const int* __restrict__ target,
                                    const float* __restrict__ colinv,
                                    unsigned char* __restrict__ Fn,
                                    float* __restrict__ ctv, float* __restrict__ cpv, int C) {
  const int wave = threadIdx.x >> 6, lane = threadIdx.x & 63;
  const int row = blockIdx.x * 4 + wave;
  const int t = target[row];
  const float* fr = f + (size_t)row * 128;
  float x0 = fr[2 * lane], x1 = fr[2 * lane + 1];
  float wt0 = w[(size_t)(2 * lane) * C + t], wt1 = w[(size_t)(2 * lane + 1) * C + t];
  float sn = x0 * x0 + x1 * x1;
  float sd = x0 * wt0 + x1 * wt1;
  #pragma unroll
  for (int m = 32; m; m >>= 1) {
    sn += __shfl_xor(sn, m);
    sd += __shfl_xor(sd, m);
  }
  const float inv = 1.0f / sqrtf(sn);   // all lanes have sn, sd
  unsigned p = (unsigned)__builtin_amdgcn_cvt_pk_fp8_f32(x0 * inv, x1 * inv, 0, false);
  *(unsigned short*)(Fn + (size_t)row * 128 + lane * 2) = (unsigned short)(p & 0xFFFFu);
  if (lane == 0) {
    float ct = sd * inv * colinv[t];
    ct = fminf(1.f, fmaxf(-1.f, ct));
    float st = sqrtf(fmaxf(0.f, 1.f - ct * ct));
    ctv[row] = ct;
    cpv[row] = ct * ANGLE_COS - st * ANGLE_SIN;
  }
}

// ---- main: R14 structure (512 thr / 8 waves, rf=2, 128-col fp8 tile 16KB,
// grid (782,8)) + R15: MX-scaled 16x16x128 MFMA with unit scales (2x fp8
// rate, 4x fewer MFMA instrs; MFMA floor ~25us -> ~11us). A/B share the same
// k<->byte mapping (granule), so K-permutation invariance of dot products
// makes the layout safe; uniform scale makes 32-block boundaries irrelevant.
template <int PREP, int ATOMIC>
__global__ __launch_bounds__(512) void arc_main_kernel(
    const float* __restrict__ w, const float* __restrict__ colinv,
    const unsigned char* __restrict__ wbn, const unsigned char* __restrict__ Fn,
    float* __restrict__ out_part, int C, int CT, int nrows) {
  __shared__ __align__(16) char smem[20480];  // max(16KB tile, 20KB reduce)
  char* Bt = smem;
  float* Rs = (float*)smem;  // reduce scratch, reused after barrier
  const int tid = threadIdx.x;

  // bijective XCD swizzle (total = nx*8): each col-tile's 8 row-groups get
  // consecutive virtual ids on one XCD -> tile L2-hot across its stagings.
  const int nx = gridDim.x;
  const int i = blockIdx.x + nx * blockIdx.y;  // hw linear id (x fastest)
  const int v = (i & 7) * nx + (i >> 3);       // XCD-contiguous virtual id
  const int vx = v >> 3;                       // col-tile
  const int vy = v & 7;                        // row-group
  const int cbase = vx << 7;

  const int wave = tid >> 6;
  const int lane = tid & 63;
  const int l15 = lane & 15;
  const int lhi = lane >> 4;
  const int ry = nrows >> 3;               // rows per row-group (256)
  const int rowbase = vy * ry + wave * 32; // 32 rows per wave

  if (PREP) {
    // 16 KB tile: wave handles q = wave, wave+8; each q-chunk is 1 KB
    // contiguous in wbn (128 granules x 8B). dest = uniform base + lane*16.
    #pragma unroll
    for (int k = 0; k < 2; ++k) {
      const int q = wave + k * 8;
      __builtin_amdgcn_global_load_lds(
          (gvoid_t*)(const void*)(wbn + ((size_t)q * CT + cbase) * 8 + lane * 16),
          (lvoid_t*)(void*)(Bt + q * 1024 + lane * 16), 16, 0, 0);
    }
  } else {
    const int c = tid & 127;
    const int dstart = tid >> 7;  // 0..3
    const int gc = cbase + c;
    const bool ok = (gc < C);
    const float cinv = ok ? colinv[gc] * LOG2E : 0.f;
    const float* wp = w + (size_t)dstart * C + gc;
    #pragma unroll 8
    for (int s = 0; s < 32; ++s) {
      const int d = dstart + 4 * s;
      float vv = ok ? wp[(size_t)(4 * s) * C] * cinv : 0.f;
      Bt[(d >> 3) * 1024 + c * 8 + (d & 7)] =
          (char)(__builtin_amdgcn_cvt_pk_fp8_f32(vv, 0.f, 0, false) & 0xFF);
    }
  }

  // A fragments (fp8, K=128: 32B per rf = i32x8) issued BEFORE the barrier.
  // Lane (l15, lhi): row = rowbase + rf*16 + l15, bytes k = lhi*32..lhi*32+31.
  i32x8 a[2];
  {
    const char* base = (const char*)Fn + (size_t)(rowbase + l15) * 128 + lhi * 32;
    #pragma unroll
    for (int rf = 0; rf < 2; ++rf)
      a[rf] = *(const i32x8*)(base + rf * 16 * 128);
  }
  __syncthreads();

  float psum[2][4];
  #pragma unroll
  for (int rf = 0; rf < 2; ++rf)
    #pragma unroll
    for (int r = 0; r < 4; ++r) psum[rf][r] = 0.f;

  // 8 col-frags: per cf, one B-frag (32B: granules q=4*lhi..4*lhi+3 of col
  // cf*16+l15 — same conflict-free addresses as R14) + 2 MFMAs + 8 exp2.
  #pragma unroll
  for (int cf = 0; cf < 8; ++cf) {
    const char* bcol = Bt + (cf * 16 + l15) * 8;
    union { long l[4]; i32x8 v; } bu;
    bu.l[0] = *(const long*)(bcol + (4 * lhi + 0) * 1024);
    bu.l[1] = *(const long*)(bcol + (4 * lhi + 1) * 1024);
    bu.l[2] = *(const long*)(bcol + (4 * lhi + 2) * 1024);
    bu.l[3] = *(const long*)(bcol + (4 * lhi + 3) * 1024);
    __builtin_amdgcn_s_setprio(1);
    f32x4 acc0 = __builtin_amdgcn_mfma_scale_f32_16x16x128_f8f6f4(
        a[0], bu.v, (f32x4){0.f, 0.f, 0.f, 0.f}, 0, 0, 0, SCALE1, 0, SCALE1);
    f32x4 acc1 = __builtin_amdgcn_mfma_scale_f32_16x16x128_f8f6f4(
        a[1], bu.v, (f32x4){0.f, 0.f, 0.f, 0.f}, 0, 0, 0, SCALE1, 0, SCALE1);
    __builtin_amdgcn_s_setprio(0);
    // D layout (16x16 shape-determined): col = lane&15, row = lhi*4 + r.
    // wbn pre-scaled by log2e -> exp(cos) == 2^acc, single v_exp_f32.
    #pragma unroll
    for (int r = 0; r < 4; ++r) {
      psum[0][r] += exp2_hw(acc0[r]);
      psum[1][r] += exp2_hw(acc1[r]);
    }
  }

  // ---- block-level reduce over the 16 l15 lanes sharing each row ----
  // scratch: [row 0..255][stride 20 floats] = 20480 B.
  __syncthreads();  // all waves done reading Bt
  #pragma unroll
  for (int rf = 0; rf < 2; ++rf)
    #pragma unroll
    for (int r = 0; r < 4; ++r) {
      const int rowlocal = wave * 32 + rf * 16 + lhi * 4 + r;
      Rs[rowlocal * 20 + l15] = psum[rf][r];
    }
  __syncthreads();
  if (tid < 256) {
    float s = 0.f;
    #pragma unroll
    for (int j = 0; j < 4; ++j) {
      f32x4 vv = *(const f32x4*)&Rs[tid * 20 + j * 4];
      s += vv[0] + vv[1] + vv[2] + vv[3];
    }
    const int row = vy * ry + tid;
    if (ATOMIC) atomicAdd(&out_part[row], s);
    else out_part[(size_t)vx * nrows + row] = s;
  }
}

// ---- fused combine + loss: per row, sum partials (coalesced across rows),
// compute log(down) - cp, block-reduce, one atomicAdd per block into out[0].
__global__ void reduce_loss_kernel(const float* __restrict__ partial,
                                   const float* __restrict__ ctv,
                                   const float* __restrict__ cpv,
                                   float* __restrict__ out,
                                   int nparts, int nrows, float pad, float invN) {
  const int tid = threadIdx.x;
  const int row = blockIdx.x * 256 + tid;
  float s = 0.f;
  #pragma unroll 4
  for (int p = 0; p < nparts; ++p) s += partial[(size_t)p * nrows + row];
  const float cp = cpv[row];
  const float top = __expf(cp);
  const float down = s - pad - __expf(ctv[row]) + top;
  float local = __logf(down) - cp;
  #pragma unroll
  for (int m = 32; m; m >>= 1) local += __shfl_xor(local, m);
  __shared__ float red[4];
  if ((tid & 63) == 0) red[tid >> 6] = local;
  __syncthreads();
  if (tid == 0) atomicAdd(out, (red[0] + red[1] + red[2] + red[3]) * invN);
}

// ---- finalize for the ATOMIC fallback path ----
__global__ void finalize_kernel(const float* __restrict__ rowsum, const float* __restrict__ ctv,
                                const float* __restrict__ cpv, float* __restrict__ out,
                                int N, float pad, float invN) {
  const int tid = threadIdx.x;
  float local = 0.f;
  for (int i = tid; i < N; i += 256) {
    float top = __expf(cpv[i]);
    float down = rowsum[i] - pad - __expf(ctv[i]) + top;
    local += __logf(down) - cpv[i];
  }
  #pragma unroll
  for (int m = 32; m; m >>= 1) local += __shfl_xor(local, m);
  __shared__ float red[4];
  if ((tid & 63) == 0) red[tid >> 6] = local;
  __syncthreads();
  if (tid == 0) out[0] = (red[0] + red[1] + red[2] + red[3]) * invN;
}

extern "C" void kernel_launch(void* const* d_in, const int* in_sizes, int n_in,
                              void* d_out, int out_size, void* d_ws, size_t ws_size,
                              hipStream_t stream) {
  const float* features = (const float*)d_in[0];
  const int* target = (const int*)d_in[1];
  const float* w = (const float*)d_in[2];
  float* out = (float*)d_out;

  const int N = in_sizes[1];          // 2048
  const int D = in_sizes[0] / N;      // 128 (layout hardcoded in kernels)
  const int C = in_sizes[2] / D;      // 100000
  (void)D;
  const int nct = (C + 127) / 128;    // 782 col tiles
  const int CT = nct * 128;           // padded col count

  char* ws = (char*)d_ws;
  size_t off = 0;
  unsigned char* Fn = (unsigned char*)(ws + off); off += (size_t)N * 128;
  off = (off + 255) & ~(size_t)255;
  float* colinv = (float*)(ws + off); off += (size_t)CT * 4;
  float* rowsum = (float*)(ws + off); off += (size_t)N * 4;
  float* ctv    = (float*)(ws + off); off += (size_t)N * 4;
  float* cpv    = (float*)(ws + off); off += (size_t)N * 4; off = (off + 255) & ~(size_t)255;
  float* partial = (float*)(ws + off);
  const size_t need_store = off + (size_t)nct * N * 4;
  const size_t wbn_off = (need_store + 255) & ~(size_t)255;
  unsigned char* wbn = (unsigned char*)(ws + wbn_off);
  const size_t need_prep = wbn_off + (size_t)CT * 128;

  const bool use_store = (ws_size >= need_store);
  const bool use_prep = (ws_size >= need_prep);

  if (use_prep) {
    colprep_kernel<<<(CT + 255) / 256, 256, 0, stream>>>(w, colinv, wbn, C, CT);
  } else {
    colnorm_kernel<<<(C + 255) / 256, 256, 0, stream>>>(w, colinv, C);
  }
  fnorm_tgtdot_kernel<<<N / 4, 256, 0, stream>>>(features, w, target, colinv, Fn, ctv, cpv, C);

  dim3 grid(nct, 8);
  if (use_store) {
    (void)hipMemsetAsync(out, 0, (size_t)out_size * sizeof(float), stream);
    if (use_prep)
      arc_main_kernel<1, 0><<<grid, 512, 0, stream>>>(w, colinv, wbn, Fn, partial, C, CT, N);
    else
      arc_main_kernel<0, 0><<<grid, 512, 0, stream>>>(w, colinv, wbn, Fn, partial, C, CT, N);
    reduce_loss_kernel<<<N / 256, 256, 0, stream>>>(partial, ctv, cpv, out, nct, N,
                                                    (float)(CT - C), 1.0f / (float)N);
  } else {
    (void)hipMemsetAsync(rowsum, 0, (size_t)N * sizeof(float), stream);
    if (use_prep)
      arc_main_kernel<1, 1><<<grid, 512, 0, stream>>>(w, colinv, wbn, Fn, rowsum, C, CT, N);
    else
      arc_main_kernel<0, 1><<<grid, 512, 0, stream>>>(w, colinv, wbn, Fn, rowsum, C, CT, N);
    finalize_kernel<<<1, 256, 0, stream>>>(rowsum, ctv, cpv, out, N,
                                           (float)(CT - C), 1.0f / (float)N);
  }
}

// Round 16
// 71.635 us; speedup vs baseline: 1.6827x; 1.6827x over previous
//
#include <hip/hip_runtime.h>
#include <hip/hip_bf16.h>

typedef __attribute__((ext_vector_type(4))) float f32x4;
typedef __attribute__((ext_vector_type(8))) int i32x8;
typedef __attribute__((ext_vector_type(2))) unsigned uintx2;
typedef const __attribute__((address_space(1))) void gvoid_t;
typedef __attribute__((address_space(3))) void lvoid_t;

#define ANGLE_COS 0.8775825618903728f  // cos(0.5)
#define ANGLE_SIN 0.4794255386042030f  // sin(0.5)
#define LOG2E 1.4426950408889634f
#define SCALE1 0x7F7F7F7Fu             // e8m0 exponent 127 = 2^0 in all bytes

static __device__ __forceinline__ float exp2_hw(float x) {
  return __builtin_amdgcn_exp2f(x);  // v_exp_f32: D = 2^S0
}

// pack 4 floats -> 4 OCP e4m3 bytes
static __device__ __forceinline__ unsigned pack4_fp8(float a, float b, float c, float d) {
  int v = __builtin_amdgcn_cvt_pk_fp8_f32(a, b, 0, false);   // bytes 0,1
  v = __builtin_amdgcn_cvt_pk_fp8_f32(c, d, v, true);        // bytes 2,3
  return (unsigned)v;
}

// ---- colprep: column inverse norms + fp8 w_norm*log2e in granule layout:
// granule (q,c) = 8B holding d = q*8..q*8+7 of column c, at wbn + (q*CT+c)*8.
__global__ __launch_bounds__(256) void colprep_kernel(
    const float* __restrict__ w, float* __restrict__ colinv,
    unsigned char* __restrict__ wbn, int C, int CT) {
  const int c = blockIdx.x * 256 + threadIdx.x;
  if (c >= CT) return;
  if (c >= C) {  // pad columns -> zeros (2^0=1, subtracted in finalize)
    colinv[c] = 0.f;
    uintx2 z; z.x = 0; z.y = 0;
    #pragma unroll
    for (int q = 0; q < 16; ++q) *(uintx2*)(wbn + ((size_t)q * CT + c) * 8) = z;
    return;
  }
  float col[128];
  float s = 0.f;
  #pragma unroll
  for (int d = 0; d < 128; ++d) {
    col[d] = w[(size_t)d * C + c];
    s += col[d] * col[d];
  }
  const float inv = 1.0f / sqrtf(s);
  colinv[c] = inv;
  const float invl = inv * LOG2E;
  #pragma unroll
  for (int q = 0; q < 16; ++q) {
    uintx2 g;
    g.x = pack4_fp8(col[q*8+0]*invl, col[q*8+1]*invl, col[q*8+2]*invl, col[q*8+3]*invl);
    g.y = pack4_fp8(col[q*8+4]*invl, col[q*8+5]*invl, col[q*8+6]*invl, col[q*8+7]*invl);
    *(uintx2*)(wbn + ((size_t)q * CT + c) * 8) = g;
  }
}

// ---- colnorm only (fallback path when ws can't hold wbn) ----
__global__ void colnorm_kernel(const float* __restrict__ w, float* __restrict__ colinv, int C) {
  int c = blockIdx.x * 256 + threadIdx.x;
  if (c >= C) return;
  float s = 0.f;
  #pragma unroll 8
  for (int d = 0; d < 128; ++d) { float v = w[(size_t)d * C + c]; s += v * v; }
  colinv[c] = 1.0f / sqrtf(s);
}

// ---- fused: row-normalize -> fp8 Fn, plus fp32 target-column dot ->
// ct (cos theta) and cp (cos(theta+m)) per row. One shuffle pass for both.
__global__ void fnorm_tgtdot_kernel(const float* __restrict__ f, const float* __restrict__ w,
                                    const int* __restrict__ target,
                                    const float* __restrict__ colinv,
                                    unsigned char* __restrict__ Fn,
                                    float* __restrict__ ctv, float* __restrict__ cpv, int C) {
  const int wave = threadIdx.x >> 6, lane = threadIdx.x & 63;
  const int row = blockIdx.x * 4 + wave;
  const int t = target[row];
  const float* fr = f + (size_t)row * 128;
  float x0 = fr[2 * lane], x1 = fr[2 * lane + 1];
  float wt0 = w[(size_t)(2 * lane) * C + t], wt1 = w[(size_t)(2 * lane + 1) * C + t];
  float sn = x0 * x0 + x1 * x1;
  float sd = x0 * wt0 + x1 * wt1;
  #pragma unroll
  for (int m = 32; m; m >>= 1) {
    sn += __shfl_xor(sn, m);
    sd += __shfl_xor(sd, m);
  }
  const float inv = 1.0f / sqrtf(sn);   // all lanes have sn, sd
  unsigned p = (unsigned)__builtin_amdgcn_cvt_pk_fp8_f32(x0 * inv, x1 * inv, 0, false);
  *(unsigned short*)(Fn + (size_t)row * 128 + lane * 2) = (unsigned short)(p & 0xFFFFu);
  if (lane == 0) {
    float ct = sd * inv * colinv[t];
    ct = fminf(1.f, fmaxf(-1.f, ct));
    float st = sqrtf(fmaxf(0.f, 1.f - ct * ct));
    ctv[row] = ct;
    cpv[row] = ct * ANGLE_COS - st * ANGLE_SIN;
  }
}

// ---- main: 512 thr / 8 waves, rf=2, 128-col fp8 tile (16KB LDS), grid
// (782,8); MX-scaled 16x16x128 MFMA, unit scales (R15 — verified correct,
// ~4x fewer MFMA instrs). A/B share the same k<->byte granule mapping (dot
// products are K-permutation invariant; uniform scale => block boundaries
// irrelevant). R16 reverts only the broken fused reduction (R15: 8-block
// reduce_loss was 63us at 50GB/s).
template <int PREP, int ATOMIC>
__global__ __launch_bounds__(512) void arc_main_kernel(
    const float* __restrict__ w, const float* __restrict__ colinv,
    const unsigned char* __restrict__ wbn, const unsigned char* __restrict__ Fn,
    float* __restrict__ out_part, int C, int CT, int nrows) {
  __shared__ __align__(16) char smem[20480];  // max(16KB tile, 20KB reduce)
  char* Bt = smem;
  float* Rs = (float*)smem;  // reduce scratch, reused after barrier
  const int tid = threadIdx.x;

  // bijective XCD swizzle (total = nx*8): each col-tile's 8 row-groups get
  // consecutive virtual ids on one XCD -> tile L2-hot across its stagings.
  const int nx = gridDim.x;
  const int i = blockIdx.x + nx * blockIdx.y;  // hw linear id (x fastest)
  const int v = (i & 7) * nx + (i >> 3);       // XCD-contiguous virtual id
  const int vx = v >> 3;                       // col-tile
  const int vy = v & 7;                        // row-group
  const int cbase = vx << 7;

  const int wave = tid >> 6;
  const int lane = tid & 63;
  const int l15 = lane & 15;
  const int lhi = lane >> 4;
  const int ry = nrows >> 3;               // rows per row-group (256)
  const int rowbase = vy * ry + wave * 32; // 32 rows per wave

  if (PREP) {
    // 16 KB tile: wave handles q = wave, wave+8; each q-chunk is 1 KB
    // contiguous in wbn (128 granules x 8B). dest = uniform base + lane*16.
    #pragma unroll
    for (int k = 0; k < 2; ++k) {
      const int q = wave + k * 8;
      __builtin_amdgcn_global_load_lds(
          (gvoid_t*)(const void*)(wbn + ((size_t)q * CT + cbase) * 8 + lane * 16),
          (lvoid_t*)(void*)(Bt + q * 1024 + lane * 16), 16, 0, 0);
    }
  } else {
    const int c = tid & 127;
    const int dstart = tid >> 7;  // 0..3
    const int gc = cbase + c;
    const bool ok = (gc < C);
    const float cinv = ok ? colinv[gc] * LOG2E : 0.f;
    const float* wp = w + (size_t)dstart * C + gc;
    #pragma unroll 8
    for (int s = 0; s < 32; ++s) {
      const int d = dstart + 4 * s;
      float vv = ok ? wp[(size_t)(4 * s) * C] * cinv : 0.f;
      Bt[(d >> 3) * 1024 + c * 8 + (d & 7)] =
          (char)(__builtin_amdgcn_cvt_pk_fp8_f32(vv, 0.f, 0, false) & 0xFF);
    }
  }

  // A fragments (fp8, K=128: 32B per rf = i32x8) issued BEFORE the barrier.
  i32x8 a[2];
  {
    const char* base = (const char*)Fn + (size_t)(rowbase + l15) * 128 + lhi * 32;
    #pragma unroll
    for (int rf = 0; rf < 2; ++rf)
      a[rf] = *(const i32x8*)(base + rf * 16 * 128);
  }
  __syncthreads();

  float psum[2][4];
  #pragma unroll
  for (int rf = 0; rf < 2; ++rf)
    #pragma unroll
    for (int r = 0; r < 4; ++r) psum[rf][r] = 0.f;

  // 8 col-frags: per cf, one B-frag (32B: granules q=4*lhi..4*lhi+3 of col
  // cf*16+l15 — conflict-free b64 reads) + 2 MFMAs + 8 exp2.
  #pragma unroll
  for (int cf = 0; cf < 8; ++cf) {
    const char* bcol = Bt + (cf * 16 + l15) * 8;
    union { long l[4]; i32x8 v; } bu;
    bu.l[0] = *(const long*)(bcol + (4 * lhi + 0) * 1024);
    bu.l[1] = *(const long*)(bcol + (4 * lhi + 1) * 1024);
    bu.l[2] = *(const long*)(bcol + (4 * lhi + 2) * 1024);
    bu.l[3] = *(const long*)(bcol + (4 * lhi + 3) * 1024);
    __builtin_amdgcn_s_setprio(1);
    f32x4 acc0 = __builtin_amdgcn_mfma_scale_f32_16x16x128_f8f6f4(
        a[0], bu.v, (f32x4){0.f, 0.f, 0.f, 0.f}, 0, 0, 0, SCALE1, 0, SCALE1);
    f32x4 acc1 = __builtin_amdgcn_mfma_scale_f32_16x16x128_f8f6f4(
        a[1], bu.v, (f32x4){0.f, 0.f, 0.f, 0.f}, 0, 0, 0, SCALE1, 0, SCALE1);
    __builtin_amdgcn_s_setprio(0);
    // D layout (16x16 shape-determined): col = lane&15, row = lhi*4 + r.
    // wbn pre-scaled by log2e -> exp(cos) == 2^acc, single v_exp_f32.
    #pragma unroll
    for (int r = 0; r < 4; ++r) {
      psum[0][r] += exp2_hw(acc0[r]);
      psum[1][r] += exp2_hw(acc1[r]);
    }
  }

  // ---- block-level reduce over the 16 l15 lanes sharing each row ----
  // scratch: [row 0..255][stride 20 floats] = 20480 B.
  __syncthreads();  // all waves done reading Bt
  #pragma unroll
  for (int rf = 0; rf < 2; ++rf)
    #pragma unroll
    for (int r = 0; r < 4; ++r) {
      const int rowlocal = wave * 32 + rf * 16 + lhi * 4 + r;
      Rs[rowlocal * 20 + l15] = psum[rf][r];
    }
  __syncthreads();
  if (tid < 256) {
    float s = 0.f;
    #pragma unroll
    for (int j = 0; j < 4; ++j) {
      f32x4 vv = *(const f32x4*)&Rs[tid * 20 + j * 4];
      s += vv[0] + vv[1] + vv[2] + vv[3];
    }
    const int row = vy * ry + tid;
    if (ATOMIC) atomicAdd(&out_part[row], s);
    else out_part[(size_t)vx * nrows + row] = s;
  }
}

// ---- combine partials: (nrows/256) row-blocks x 16 part-slices ----
__global__ void reduce_kernel(const float* __restrict__ partial, float* __restrict__ rowsum,
                              int nparts, int nrows) {
  const int nrb = nrows >> 8;
  const int row = (blockIdx.x % nrb) * 256 + threadIdx.x;
  const int slice = blockIdx.x / nrb;
  const int pper = (nparts + 15) / 16;
  const int p0 = slice * pper;
  const int p1 = min(nparts, p0 + pper);
  float s = 0.f;
  #pragma unroll 4
  for (int p = p0; p < p1; ++p) s += partial[(size_t)p * nrows + row];
  atomicAdd(&rowsum[row], s);
}

// ---- finalize: loss = mean( log(down_i) - cosplus_i ) ----
__global__ void finalize_kernel(const float* __restrict__ rowsum, const float* __restrict__ ctv,
                                const float* __restrict__ cpv, float* __restrict__ out,
                                int N, float pad, float invN) {
  const int tid = threadIdx.x;
  float local = 0.f;
  for (int i = tid; i < N; i += 256) {
    float top = __expf(cpv[i]);
    float down = rowsum[i] - pad - __expf(ctv[i]) + top;
    local += __logf(down) - cpv[i];
  }
  #pragma unroll
  for (int m = 32; m; m >>= 1) local += __shfl_xor(local, m);
  __shared__ float red[4];
  if ((tid & 63) == 0) red[tid >> 6] = local;
  __syncthreads();
  if (tid == 0) out[0] = (red[0] + red[1] + red[2] + red[3]) * invN;
}

extern "C" void kernel_launch(void* const* d_in, const int* in_sizes, int n_in,
                              void* d_out, int out_size, void* d_ws, size_t ws_size,
                              hipStream_t stream) {
  const float* features = (const float*)d_in[0];
  const int* target = (const int*)d_in[1];
  const float* w = (const float*)d_in[2];
  float* out = (float*)d_out;

  const int N = in_sizes[1];          // 2048
  const int D = in_sizes[0] / N;      // 128 (layout hardcoded in kernels)
  const int C = in_sizes[2] / D;      // 100000
  (void)D;
  const int nct = (C + 127) / 128;    // 782 col tiles
  const int CT = nct * 128;           // padded col count

  char* ws = (char*)d_ws;
  size_t off = 0;
  unsigned char* Fn = (unsigned char*)(ws + off); off += (size_t)N * 128;
  off = (off + 255) & ~(size_t)255;
  float* colinv = (float*)(ws + off); off += (size_t)CT * 4;
  float* rowsum = (float*)(ws + off); off += (size_t)N * 4;
  float* ctv    = (float*)(ws + off); off += (size_t)N * 4;
  float* cpv    = (float*)(ws + off); off += (size_t)N * 4; off = (off + 255) & ~(size_t)255;
  float* partial = (float*)(ws + off);
  const size_t need_store = off + (size_t)nct * N * 4;
  const size_t wbn_off = (need_store + 255) & ~(size_t)255;
  unsigned char* wbn = (unsigned char*)(ws + wbn_off);
  const size_t need_prep = wbn_off + (size_t)CT * 128;

  const bool use_store = (ws_size >= need_store);
  const bool use_prep = (ws_size >= need_prep);

  (void)hipMemsetAsync(rowsum, 0, (size_t)N * sizeof(float), stream);
  if (use_prep) {
    colprep_kernel<<<(CT + 255) / 256, 256, 0, stream>>>(w, colinv, wbn, C, CT);
  } else {
    colnorm_kernel<<<(C + 255) / 256, 256, 0, stream>>>(w, colinv, C);
  }
  fnorm_tgtdot_kernel<<<N / 4, 256, 0, stream>>>(features, w, target, colinv, Fn, ctv, cpv, C);

  dim3 grid(nct, 8);
  if (use_store) {
    if (use_prep)
      arc_main_kernel<1, 0><<<grid, 512, 0, stream>>>(w, colinv, wbn, Fn, partial, C, CT, N);
    else
      arc_main_kernel<0, 0><<<grid, 512, 0, stream>>>(w, colinv, wbn, Fn, partial, C, CT, N);
    reduce_kernel<<<(N / 256) * 16, 256, 0, stream>>>(partial, rowsum, nct, N);
  } else {
    if (use_prep)
      arc_main_kernel<1, 1><<<grid, 512, 0, stream>>>(w, colinv, wbn, Fn, rowsum, C, CT, N);
    else
      arc_main_kernel<0, 1><<<grid, 512, 0, stream>>>(w, colinv, wbn, Fn, rowsum, C, CT, N);
  }
  finalize_kernel<<<1, 256, 0, stream>>>(rowsum, ctv, cpv, out, N,
                                         (float)(CT - C), 1.0f / (float)N);
}

// Round 17
// 66.825 us; speedup vs baseline: 1.8038x; 1.0720x over previous
//
#include <hip/hip_runtime.h>
#include <hip/hip_bf16.h>

typedef __attribute__((ext_vector_type(4))) float f32x4;
typedef __attribute__((ext_vector_type(8))) int i32x8;
typedef __attribute__((ext_vector_type(2))) unsigned uintx2;
typedef const __attribute__((address_space(1))) void gvoid_t;
typedef __attribute__((address_space(3))) void lvoid_t;

#define ANGLE_COS 0.8775825618903728f  // cos(0.5)
#define ANGLE_SIN 0.4794255386042030f  // sin(0.5)
#define LOG2E 1.4426950408889634f
#define SCALE1 0x7F7F7F7Fu             // e8m0 exponent 127 = 2^0 in all bytes

static __device__ __forceinline__ float exp2_hw(float x) {
  return __builtin_amdgcn_exp2f(x);  // v_exp_f32: D = 2^S0
}

// pack 4 floats -> 4 OCP e4m3 bytes
static __device__ __forceinline__ unsigned pack4_fp8(float a, float b, float c, float d) {
  int v = __builtin_amdgcn_cvt_pk_fp8_f32(a, b, 0, false);   // bytes 0,1
  v = __builtin_amdgcn_cvt_pk_fp8_f32(c, d, v, true);        // bytes 2,3
  return (unsigned)v;
}

// ---- colprep: column inverse norms + fp8 w_norm*log2e in granule layout:
// granule (q,c) = 8B holding d = q*8..q*8+7 of column c, at wbn + (q*CT+c)*8.
__global__ __launch_bounds__(256) void colprep_kernel(
    const float* __restrict__ w, float* __restrict__ colinv,
    unsigned char* __restrict__ wbn, int C, int CT) {
  const int c = blockIdx.x * 256 + threadIdx.x;
  if (c >= CT) return;
  if (c >= C) {  // pad columns -> zeros (2^0=1, subtracted in finalize)
    colinv[c] = 0.f;
    uintx2 z; z.x = 0; z.y = 0;
    #pragma unroll
    for (int q = 0; q < 16; ++q) *(uintx2*)(wbn + ((size_t)q * CT + c) * 8) = z;
    return;
  }
  float col[128];
  float s = 0.f;
  #pragma unroll
  for (int d = 0; d < 128; ++d) {
    col[d] = w[(size_t)d * C + c];
    s += col[d] * col[d];
  }
  const float inv = 1.0f / sqrtf(s);
  colinv[c] = inv;
  const float invl = inv * LOG2E;
  #pragma unroll
  for (int q = 0; q < 16; ++q) {
    uintx2 g;
    g.x = pack4_fp8(col[q*8+0]*invl, col[q*8+1]*invl, col[q*8+2]*invl, col[q*8+3]*invl);
    g.y = pack4_fp8(col[q*8+4]*invl, col[q*8+5]*invl, col[q*8+6]*invl, col[q*8+7]*invl);
    *(uintx2*)(wbn + ((size_t)q * CT + c) * 8) = g;
  }
}

// ---- colnorm only (fallback path when ws can't hold wbn) ----
__global__ void colnorm_kernel(const float* __restrict__ w, float* __restrict__ colinv, int C) {
  int c = blockIdx.x * 256 + threadIdx.x;
  if (c >= C) return;
  float s = 0.f;
  #pragma unroll 8
  for (int d = 0; d < 128; ++d) { float v = w[(size_t)d * C + c]; s += v * v; }
  colinv[c] = 1.0f / sqrtf(s);
}

// ---- fused: row-normalize -> fp8 Fn, fp32 target-column dot -> ct/cp,
// and rowsum zero-init (replaces the 40us-profiled hipMemsetAsync launch).
__global__ void fnorm_tgtdot_kernel(const float* __restrict__ f, const float* __restrict__ w,
                                    const int* __restrict__ target,
                                    const float* __restrict__ colinv,
                                    unsigned char* __restrict__ Fn,
                                    float* __restrict__ ctv, float* __restrict__ cpv,
                                    float* __restrict__ rowsum, int C) {
  const int wave = threadIdx.x >> 6, lane = threadIdx.x & 63;
  const int row = blockIdx.x * 4 + wave;
  const int t = target[row];
  const float* fr = f + (size_t)row * 128;
  float x0 = fr[2 * lane], x1 = fr[2 * lane + 1];
  float wt0 = w[(size_t)(2 * lane) * C + t], wt1 = w[(size_t)(2 * lane + 1) * C + t];
  float sn = x0 * x0 + x1 * x1;
  float sd = x0 * wt0 + x1 * wt1;
  #pragma unroll
  for (int m = 32; m; m >>= 1) {
    sn += __shfl_xor(sn, m);
    sd += __shfl_xor(sd, m);
  }
  const float inv = 1.0f / sqrtf(sn);   // all lanes have sn, sd
  unsigned p = (unsigned)__builtin_amdgcn_cvt_pk_fp8_f32(x0 * inv, x1 * inv, 0, false);
  *(unsigned short*)(Fn + (size_t)row * 128 + lane * 2) = (unsigned short)(p & 0xFFFFu);
  if (lane == 0) {
    float ct = sd * inv * colinv[t];
    ct = fminf(1.f, fmaxf(-1.f, ct));
    float st = sqrtf(fmaxf(0.f, 1.f - ct * ct));
    ctv[row] = ct;
    cpv[row] = ct * ANGLE_COS - st * ANGLE_SIN;
    rowsum[row] = 0.f;
  }
}

// ---- main: 512 thr / 8 waves, rf=4 (64 rows/wave -> 512-row block), 128-col
// fp8 tile (16KB LDS), grid (782,4); MX-scaled 16x16x128 MFMA, unit scales.
// R17: rf 2->4 halves the per-output LDS B re-read (the largest pipe floor,
// ~15us). fp8 K=128 A-frags are only 8 VGPR per rf, so the R10 VGPR blowup
// doesn't apply — mechanism check: VGPR <= 64. Tail scratch 40KB LDS ->
// 4 blocks/CU x 8 waves = 32 waves/CU (still max).
template <int PREP, int ATOMIC>
__global__ __launch_bounds__(512) void arc_main_kernel(
    const float* __restrict__ w, const float* __restrict__ colinv,
    const unsigned char* __restrict__ wbn, const unsigned char* __restrict__ Fn,
    float* __restrict__ out_part, int C, int CT, int nrows) {
  __shared__ __align__(16) char smem[40960];  // max(16KB tile, 40KB reduce)
  char* Bt = smem;
  float* Rs = (float*)smem;  // reduce scratch, reused after barrier
  const int tid = threadIdx.x;

  // bijective XCD swizzle (total = nx*4 = 8*391): each col-tile's 4
  // row-groups get consecutive virtual ids on one XCD -> tile L2-hot.
  const int nx = gridDim.x;
  const int i = blockIdx.x + nx * blockIdx.y;   // hw linear id (x fastest)
  const int v = (i & 7) * (nx >> 1) + (i >> 3); // XCD-contiguous virtual id
  const int vx = v >> 2;                        // col-tile
  const int vy = v & 3;                         // row-group
  const int cbase = vx << 7;

  const int wave = tid >> 6;
  const int lane = tid & 63;
  const int l15 = lane & 15;
  const int lhi = lane >> 4;
  const int ry = nrows >> 2;               // rows per row-group (512)
  const int rowbase = vy * ry + wave * 64; // 64 rows per wave

  if (PREP) {
    // 16 KB tile: wave handles q = wave, wave+8; each q-chunk is 1 KB
    // contiguous in wbn (128 granules x 8B). dest = uniform base + lane*16.
    #pragma unroll
    for (int k = 0; k < 2; ++k) {
      const int q = wave + k * 8;
      __builtin_amdgcn_global_load_lds(
          (gvoid_t*)(const void*)(wbn + ((size_t)q * CT + cbase) * 8 + lane * 16),
          (lvoid_t*)(void*)(Bt + q * 1024 + lane * 16), 16, 0, 0);
    }
  } else {
    const int c = tid & 127;
    const int dstart = tid >> 7;  // 0..3
    const int gc = cbase + c;
    const bool ok = (gc < C);
    const float cinv = ok ? colinv[gc] * LOG2E : 0.f;
    const float* wp = w + (size_t)dstart * C + gc;
    #pragma unroll 8
    for (int s = 0; s < 32; ++s) {
      const int d = dstart + 4 * s;
      float vv = ok ? wp[(size_t)(4 * s) * C] * cinv : 0.f;
      Bt[(d >> 3) * 1024 + c * 8 + (d & 7)] =
          (char)(__builtin_amdgcn_cvt_pk_fp8_f32(vv, 0.f, 0, false) & 0xFF);
    }
  }

  // A fragments (fp8, K=128: 32B per rf = i32x8) issued BEFORE the barrier.
  i32x8 a[4];
  {
    const char* base = (const char*)Fn + (size_t)(rowbase + l15) * 128 + lhi * 32;
    #pragma unroll
    for (int rf = 0; rf < 4; ++rf)
      a[rf] = *(const i32x8*)(base + rf * 16 * 128);
  }
  __syncthreads();

  float psum[4][4];
  #pragma unroll
  for (int rf = 0; rf < 4; ++rf)
    #pragma unroll
    for (int r = 0; r < 4; ++r) psum[rf][r] = 0.f;

  // 8 col-frags: per cf, one B-frag (32B: granules q=4*lhi..4*lhi+3 of col
  // cf*16+l15 — conflict-free b64 reads) + 4 MFMAs + 16 exp2.
  #pragma unroll
  for (int cf = 0; cf < 8; ++cf) {
    const char* bcol = Bt + (cf * 16 + l15) * 8;
    union { long l[4]; i32x8 v; } bu;
    bu.l[0] = *(const long*)(bcol + (4 * lhi + 0) * 1024);
    bu.l[1] = *(const long*)(bcol + (4 * lhi + 1) * 1024);
    bu.l[2] = *(const long*)(bcol + (4 * lhi + 2) * 1024);
    bu.l[3] = *(const long*)(bcol + (4 * lhi + 3) * 1024);
    __builtin_amdgcn_s_setprio(1);
    f32x4 acc0 = __builtin_amdgcn_mfma_scale_f32_16x16x128_f8f6f4(
        a[0], bu.v, (f32x4){0.f, 0.f, 0.f, 0.f}, 0, 0, 0, SCALE1, 0, SCALE1);
    f32x4 acc1 = __builtin_amdgcn_mfma_scale_f32_16x16x128_f8f6f4(
        a[1], bu.v, (f32x4){0.f, 0.f, 0.f, 0.f}, 0, 0, 0, SCALE1, 0, SCALE1);
    f32x4 acc2 = __builtin_amdgcn_mfma_scale_f32_16x16x128_f8f6f4(
        a[2], bu.v, (f32x4){0.f, 0.f, 0.f, 0.f}, 0, 0, 0, SCALE1, 0, SCALE1);
    f32x4 acc3 = __builtin_amdgcn_mfma_scale_f32_16x16x128_f8f6f4(
        a[3], bu.v, (f32x4){0.f, 0.f, 0.f, 0.f}, 0, 0, 0, SCALE1, 0, SCALE1);
    __builtin_amdgcn_s_setprio(0);
    // D layout (16x16 shape-determined): col = lane&15, row = lhi*4 + r.
    // wbn pre-scaled by log2e -> exp(cos) == 2^acc, single v_exp_f32.
    #pragma unroll
    for (int r = 0; r < 4; ++r) {
      psum[0][r] += exp2_hw(acc0[r]);
      psum[1][r] += exp2_hw(acc1[r]);
      psum[2][r] += exp2_hw(acc2[r]);
      psum[3][r] += exp2_hw(acc3[r]);
    }
  }

  // ---- block-level reduce over the 16 l15 lanes sharing each row ----
  // scratch: [row 0..511][stride 20 floats] = 40960 B.
  __syncthreads();  // all waves done reading Bt
  #pragma unroll
  for (int rf = 0; rf < 4; ++rf)
    #pragma unroll
    for (int r = 0; r < 4; ++r) {
      const int rowlocal = wave * 64 + rf * 16 + lhi * 4 + r;
      Rs[rowlocal * 20 + l15] = psum[rf][r];
    }
  __syncthreads();
  {
    float s = 0.f;
    #pragma unroll
    for (int j = 0; j < 4; ++j) {
      f32x4 vv = *(const f32x4*)&Rs[tid * 20 + j * 4];
      s += vv[0] + vv[1] + vv[2] + vv[3];
    }
    const int row = vy * ry + tid;
    if (ATOMIC) atomicAdd(&out_part[row], s);
    else out_part[(size_t)vx * nrows + row] = s;
  }
}

// ---- combine partials: (nrows/256) row-blocks x 16 part-slices ----
__global__ void reduce_kernel(const float* __restrict__ partial, float* __restrict__ rowsum,
                              int nparts, int nrows) {
  const int nrb = nrows >> 8;
  const int row = (blockIdx.x % nrb) * 256 + threadIdx.x;
  const int slice = blockIdx.x / nrb;
  const int pper = (nparts + 15) / 16;
  const int p0 = slice * pper;
  const int p1 = min(nparts, p0 + pper);
  float s = 0.f;
  #pragma unroll 4
  for (int p = p0; p < p1; ++p) s += partial[(size_t)p * nrows + row];
  atomicAdd(&rowsum[row], s);
}

// ---- finalize: loss = mean( log(down_i) - cosplus_i ) ----
__global__ void finalize_kernel(const float* __restrict__ rowsum, const float* __restrict__ ctv,
                                const float* __restrict__ cpv, float* __restrict__ out,
                                int N, float pad, float invN) {
  const int tid = threadIdx.x;
  float local = 0.f;
  for (int i = tid; i < N; i += 256) {
    float top = __expf(cpv[i]);
    float down = rowsum[i] - pad - __expf(ctv[i]) + top;
    local += __logf(down) - cpv[i];
  }
  #pragma unroll
  for (int m = 32; m; m >>= 1) local += __shfl_xor(local, m);
  __shared__ float red[4];
  if ((tid & 63) == 0) red[tid >> 6] = local;
  __syncthreads();
  if (tid == 0) out[0] = (red[0] + red[1] + red[2] + red[3]) * invN;
}

extern "C" void kernel_launch(void* const* d_in, const int* in_sizes, int n_in,
                              void* d_out, int out_size, void* d_ws, size_t ws_size,
                              hipStream_t stream) {
  const float* features = (const float*)d_in[0];
  const int* target = (const int*)d_in[1];
  const float* w = (const float*)d_in[2];
  float* out = (float*)d_out;

  const int N = in_sizes[1];          // 2048
  const int D = in_sizes[0] / N;      // 128 (layout hardcoded in kernels)
  const int C = in_sizes[2] / D;      // 100000
  (void)D;
  const int nct = (C + 127) / 128;    // 782 col tiles
  const int CT = nct * 128;           // padded col count

  char* ws = (char*)d_ws;
  size_t off = 0;
  unsigned char* Fn = (unsigned char*)(ws + off); off += (size_t)N * 128;
  off = (off + 255) & ~(size_t)255;
  float* colinv = (float*)(ws + off); off += (size_t)CT * 4;
  float* rowsum = (float*)(ws + off); off += (size_t)N * 4;
  float* ctv    = (float*)(ws + off); off += (size_t)N * 4;
  float* cpv    = (float*)(ws + off); off += (size_t)N * 4; off = (off + 255) & ~(size_t)255;
  float* partial = (float*)(ws + off);
  const size_t need_store = off + (size_t)nct * N * 4;
  const size_t wbn_off = (need_store + 255) & ~(size_t)255;
  unsigned char* wbn = (unsigned char*)(ws + wbn_off);
  const size_t need_prep = wbn_off + (size_t)CT * 128;

  const bool use_store = (ws_size >= need_store);
  const bool use_prep = (ws_size >= need_prep);

  if (use_prep) {
    colprep_kernel<<<(CT + 255) / 256, 256, 0, stream>>>(w, colinv, wbn, C, CT);
  } else {
    colnorm_kernel<<<(C + 255) / 256, 256, 0, stream>>>(w, colinv, C);
  }
  fnorm_tgtdot_kernel<<<N / 4, 256, 0, stream>>>(features, w, target, colinv, Fn, ctv, cpv,
                                                 rowsum, C);

  dim3 grid(nct, 4);
  if (use_store) {
    if (use_prep)
      arc_main_kernel<1, 0><<<grid, 512, 0, stream>>>(w, colinv, wbn, Fn, partial, C, CT, N);
    else
      arc_main_kernel<0, 0><<<grid, 512, 0, stream>>>(w, colinv, wbn, Fn, partial, C, CT, N);
    reduce_kernel<<<(N / 256) * 16, 256, 0, stream>>>(partial, rowsum, nct, N);
  } else {
    if (use_prep)
      arc_main_kernel<1, 1><<<grid, 512, 0, stream>>>(w, colinv, wbn, Fn, rowsum, C, CT, N);
    else
      arc_main_kernel<0, 1><<<grid, 512, 0, stream>>>(w, colinv, wbn, Fn, rowsum, C, CT, N);
  }
  finalize_kernel<<<1, 256, 0, stream>>>(rowsum, ctv, cpv, out, N,
                                         (float)(CT - C), 1.0f / (float)N);
}